// Round 6
// baseline (526.531 us; speedup 1.0000x reference)
//
#include <hip/hip_runtime.h>
#include <hip/hip_cooperative_groups.h>

namespace cg = cooperative_groups;

#define B_   2
#define L_   1024
#define D_   1024
#define H_   8
#define DV_  1536
#define HDV_ 12288          // H_*DV_
#define INV_L (1.0f/1024.0f)
#define NBLK 2048
#define ATT0 9000           // atten rows written in phase 0
#define ATT1 (16384 - ATT0) // atten rows written in phase 1

// ws layout (floats):
//   part : [0, 65536)        2*32*1024 partial column sums of v
//   vsum : [65536, 67584)    2*1024
//   S    : [67584, 92160)    2*12288
//   Gp   : [92160, 100352)   2 halves * 4 (b0p0,b0p1,b1p0,b1p1) * 1024

// atten[i,q,:] = mask[i%2, q] ? 1/1024 : 0   (one block writes one 4 KB row)
__device__ __forceinline__ void atten_row(const int* __restrict__ mask,
                                          float* __restrict__ atten,
                                          int r, int t) {
    int i  = r >> 10;            // 0..15
    int qi = r & 1023;
    float val = (mask[((i & 1) << 10) + qi] != 0) ? INV_L : 0.f;
    ((float4*)(atten + (size_t)r * L_))[t] = make_float4(val, val, val, val);
}

__global__ void __launch_bounds__(256, 8)
mega(const float* __restrict__ v,   const float* __restrict__ q,
     const int*   __restrict__ mask,
     const float* __restrict__ wv,  const float* __restrict__ bv,
     const float* __restrict__ fcw,
     const float* __restrict__ lns, const float* __restrict__ lnb,
     float* __restrict__ out,  float* __restrict__ atten,
     float* __restrict__ part, float* __restrict__ vsum,
     float* __restrict__ S,    float* __restrict__ Gp) {
    cg::grid_group grid = cg::this_grid();
    __shared__ float red[16];
    const int t    = threadIdx.x;
    const int lane = t & 63;
    const int wid  = t >> 6;
    const int nb   = gridDim.x;

    // ---- P0: 64 part units (32-row float4 column sums of v) + atten filler
    for (int u = blockIdx.x; u < 64 + ATT0; u += nb) {
        if (u < 64) {
            int b = u >> 5, kch = u & 31;
            const float4* vp = (const float4*)(v + ((size_t)b * L_ + (size_t)kch * 32) * D_);
            float4 s = make_float4(0.f, 0.f, 0.f, 0.f);
            #pragma unroll
            for (int k = 0; k < 32; ++k) {
                float4 x = vp[(size_t)k * (D_ / 4) + t];
                s.x += x.x; s.y += x.y; s.z += x.z; s.w += x.w;
            }
            ((float4*)(part + ((size_t)b * 32 + kch) * D_))[t] = s;
        } else {
            atten_row(mask, atten, u - 64, t);
        }
    }
    grid.sync();

    // ---- P1: 2 vsum-reduce units + atten filler
    for (int u = blockIdx.x; u < 2 + ATT1; u += nb) {
        if (u < 2) {
            float4 s = make_float4(0.f, 0.f, 0.f, 0.f);
            #pragma unroll
            for (int kch = 0; kch < 32; ++kch) {
                float4 x = ((const float4*)(part + ((size_t)u * 32 + kch) * D_))[t];
                s.x += x.x; s.y += x.y; s.z += x.z; s.w += x.w;
            }
            ((float4*)(vsum + (size_t)u * D_))[t] = s;
        } else {
            atten_row(mask, atten, u - 2 + ATT0, t);
        }
    }
    grid.sync();

    // ---- P2: vproj. 3072 units; unit = 4 m-rows, one per wave.
    // S[b,m] = vsum[b,:] . wv[m,:] + L*bv[m]
    for (int u = blockIdx.x; u < 3072; u += nb) {
        int m = u * 4 + wid;
        const float4* row = (const float4*)(wv + (size_t)m * D_);
        const float4* v0  = (const float4*)vsum;
        const float4* v1  = (const float4*)(vsum + D_);
        float a0 = 0.f, a1 = 0.f;
        #pragma unroll
        for (int it = 0; it < 4; ++it) {        // 256 float4s / 64 lanes
            int c = it * 64 + lane;
            float4 w4 = row[c];
            float4 s0 = v0[c];
            float4 s1 = v1[c];
            a0 += w4.x*s0.x + w4.y*s0.y + w4.z*s0.z + w4.w*s0.w;
            a1 += w4.x*s1.x + w4.y*s1.y + w4.z*s1.z + w4.w*s1.w;
        }
        #pragma unroll
        for (int off = 32; off; off >>= 1) {
            a0 += __shfl_down(a0, off);
            a1 += __shfl_down(a1, off);
        }
        if (lane == 0) {
            float bb = bv[m] * (float)L_;
            S[m]        = a0 + bb;
            S[HDV_ + m] = a1 + bb;
        }
    }
    grid.sync();

    // ---- P3: fc. 2048 units; unit = (j, half). Gp[half][2b+p][j] partials.
    for (int u = blockIdx.x; u < 2048; u += nb) {
        int j = u >> 1, half = u & 1;
        const float4* row = (const float4*)(fcw + (size_t)j * HDV_);
        const float4* S0  = (const float4*)S;
        const float4* S1  = (const float4*)(S + HDV_);
        float g00 = 0.f, g01 = 0.f, g10 = 0.f, g11 = 0.f;
        #pragma unroll
        for (int it = 0; it < 6; ++it) {        // 1536 float4s / 256 thr
            int t4 = half * 1536 + it * 256 + t;
            int p  = (t4 / 384) & 1;            // 384 = DV_/4, float4 never straddles
            float4 w4 = row[t4];
            float4 s0 = S0[t4];
            float4 s1 = S1[t4];
            float d0 = w4.x*s0.x + w4.y*s0.y + w4.z*s0.z + w4.w*s0.w;
            float d1 = w4.x*s1.x + w4.y*s1.y + w4.z*s1.z + w4.w*s1.w;
            if (p) { g01 += d0; g11 += d1; } else { g00 += d0; g10 += d1; }
        }
        #pragma unroll
        for (int off = 32; off; off >>= 1) {
            g00 += __shfl_down(g00, off);
            g01 += __shfl_down(g01, off);
            g10 += __shfl_down(g10, off);
            g11 += __shfl_down(g11, off);
        }
        if (lane == 0) {
            red[wid * 4 + 0] = g00; red[wid * 4 + 1] = g01;
            red[wid * 4 + 2] = g10; red[wid * 4 + 3] = g11;
        }
        __syncthreads();
        if (t < 4) {
            float x = red[t] + red[4 + t] + red[8 + t] + red[12 + t];
            Gp[((size_t)half * 4 + t) * D_ + j] = x;   // t: 0=b0p0 1=b0p1 2=b1p0 3=b1p1
        }
        __syncthreads();
    }
    grid.sync();

    // ---- P4: ln. 2048 units; unit = one output row.
    for (int u = blockIdx.x; u < 2048; u += nb) {
        int b  = u >> 10;
        int qi = u & 1023;
        float m0 = (mask[qi]      != 0) ? INV_L : 0.f;
        float m1 = (mask[L_ + qi] != 0) ? INV_L : 0.f;
        const float4* q4  = (const float4*)(q + (size_t)u * D_);
        const float4* gA0 = (const float4*)(Gp + (size_t)(2 * b) * D_);
        const float4* gA1 = (const float4*)(Gp + (size_t)(2 * b + 1) * D_);
        const float4* gB0 = (const float4*)(Gp + (size_t)(4 + 2 * b) * D_);
        const float4* gB1 = (const float4*)(Gp + (size_t)(4 + 2 * b + 1) * D_);
        float4 a  = q4[t];
        float4 u0 = gA0[t], u1 = gB0[t];
        float4 w0 = gA1[t], w1 = gB1[t];
        float4 x;
        x.x = a.x + m0 * (u0.x + u1.x) + m1 * (w0.x + w1.x);
        x.y = a.y + m0 * (u0.y + u1.y) + m1 * (w0.y + w1.y);
        x.z = a.z + m0 * (u0.z + u1.z) + m1 * (w0.z + w1.z);
        x.w = a.w + m0 * (u0.w + u1.w) + m1 * (w0.w + w1.w);
        float s  = x.x + x.y + x.z + x.w;
        float ss = x.x*x.x + x.y*x.y + x.z*x.z + x.w*x.w;
        #pragma unroll
        for (int off = 32; off; off >>= 1) {
            s  += __shfl_down(s, off);
            ss += __shfl_down(ss, off);
        }
        if (lane == 0) { red[wid] = s; red[4 + wid] = ss; }
        __syncthreads();
        if (t == 0) {
            float sAll  = red[0] + red[1] + red[2] + red[3];
            float ssAll = red[4] + red[5] + red[6] + red[7];
            float mu  = sAll * INV_L;
            float var = ssAll * INV_L - mu * mu;
            red[0] = mu;
            red[1] = rsqrtf(var + 1e-5f);
        }
        __syncthreads();
        float mu = red[0], inv = red[1];
        float4 sc = ((const float4*)lns)[t];
        float4 bi = ((const float4*)lnb)[t];
        float4 o;
        o.x = (x.x - mu) * inv * sc.x + bi.x;
        o.y = (x.y - mu) * inv * sc.y + bi.y;
        o.z = (x.z - mu) * inv * sc.z + bi.z;
        o.w = (x.w - mu) * inv * sc.w + bi.w;
        ((float4*)(out + (size_t)u * D_))[t] = o;
        __syncthreads();
    }
}

extern "C" void kernel_launch(void* const* d_in, const int* in_sizes, int n_in,
                              void* d_out, int out_size, void* d_ws, size_t ws_size,
                              hipStream_t stream) {
    const float* q    = (const float*)d_in[0];
    const float* v    = (const float*)d_in[2];
    const int*   mask = (const int*)d_in[3];
    const float* wv   = (const float*)d_in[8];   // w_vs_w
    const float* bv   = (const float*)d_in[9];   // w_vs_b
    const float* fcw  = (const float*)d_in[10];  // fc_w
    const float* lns  = (const float*)d_in[11];
    const float* lnb  = (const float*)d_in[12];

    float* out   = (float*)d_out;
    float* atten = out + (size_t)B_ * L_ * D_;

    float* ws   = (float*)d_ws;
    float* part = ws;
    float* vsum = ws + 65536;
    float* S    = ws + 67584;
    float* Gp   = ws + 92160;

    int occ = 8;
    if (hipOccupancyMaxActiveBlocksPerMultiprocessor(&occ, (const void*)mega, 256, 0)
        != hipSuccess || occ < 1) occ = 8;
    int grid = occ * 256;            // 256 CUs
    if (grid > NBLK) grid = NBLK;

    void* args[] = { (void*)&v, (void*)&q, (void*)&mask, (void*)&wv, (void*)&bv,
                     (void*)&fcw, (void*)&lns, (void*)&lnb,
                     (void*)&out, (void*)&atten, (void*)&part, (void*)&vsum,
                     (void*)&S, (void*)&Gp };
    hipLaunchCooperativeKernel((const void*)mega, dim3(grid), dim3(256),
                               args, 0, stream);
}

// Round 7
// 40.831 us; speedup vs baseline: 12.8952x; 12.8952x over previous
//
#include <hip/hip_runtime.h>
#include <hip/hip_bf16.h>

#define B_   2
#define L_   1024
#define D_   1024
#define H_   8
#define DV_  1536
#define HDV_ 12288          // H_*DV_
#define INV_L (1.0f/1024.0f)

// ws layout (floats):
//   vsum : [0, 2048)         2*1024 column sums of v
//   S    : [2048, 26624)     2*12288
//   G    : [26624, 30720)    4*1024   order: b0p0, b0p1, b1p0, b1p1

// atten[i,q,:] = mask[i%2, q] ? 1/1024 : 0   (one block writes one 4 KB row)
__device__ __forceinline__ void atten_row(const int* __restrict__ mask,
                                          float* __restrict__ atten,
                                          int r, int t) {
    int i  = r >> 10;            // 0..15
    int qi = r & 1023;
    float val = (mask[((i & 1) << 10) + qi] != 0) ? INV_L : 0.f;
    ((float4*)(atten + (size_t)r * L_))[t] = make_float4(val, val, val, val);
}

// ---- K1: blocks [0,32) = direct vsum (batch b, 64-col strip s, all 1024 rows)
//          blocks [32, 32+16384) = atten rows
__global__ void __launch_bounds__(256) k1(const float* __restrict__ v,
                                          float* __restrict__ vsum,
                                          const int* __restrict__ mask,
                                          float* __restrict__ atten) {
    int bx = blockIdx.x, t = threadIdx.x;
    if (bx < 32) {
        __shared__ float4 lds[16][16];
        int b  = bx >> 4;            // batch
        int s  = bx & 15;            // 64-column strip
        int c4 = t & 15;             // float4 column within strip
        int rg = t >> 4;             // 16 row-groups of 64 rows
        const float4* vp = (const float4*)(v + (size_t)b * L_ * D_)
                           + (size_t)s * 16 + c4;
        float4 acc = make_float4(0.f, 0.f, 0.f, 0.f);
        #pragma unroll 8
        for (int r = 0; r < 64; ++r) {
            float4 x = vp[(size_t)(rg * 64 + r) * (D_ / 4)];
            acc.x += x.x; acc.y += x.y; acc.z += x.z; acc.w += x.w;
        }
        lds[rg][c4] = acc;
        __syncthreads();
        if (t < 16) {                // t = c4
            float4 a = make_float4(0.f, 0.f, 0.f, 0.f);
            #pragma unroll
            for (int g = 0; g < 16; ++g) {
                float4 x = lds[g][t];
                a.x += x.x; a.y += x.y; a.z += x.z; a.w += x.w;
            }
            ((float4*)(vsum + (size_t)b * D_ + (size_t)s * 64))[t] = a;
        }
    } else {
        atten_row(mask, atten, bx - 32, t);
    }
}

// ---- K2: S[b,m] = vsum[b,:] . w_vs_w[m,:] + L*b_vs[m]  (one wave per m) ----
__global__ void __launch_bounds__(256) k_vproj(const float* __restrict__ vsum,
                                               const float* __restrict__ wv,
                                               const float* __restrict__ bv,
                                               float* __restrict__ S) {
    int gid  = blockIdx.x * 256 + threadIdx.x;
    int m    = gid >> 6;
    int lane = threadIdx.x & 63;
    const float4* row = (const float4*)(wv + (size_t)m * D_);
    const float4* v0  = (const float4*)vsum;
    const float4* v1  = (const float4*)(vsum + D_);
    float a0 = 0.f, a1 = 0.f;
    #pragma unroll
    for (int it = 0; it < 4; ++it) {            // D_/4 = 256 float4s / 64 lanes
        int c = it * 64 + lane;
        float4 w4 = row[c];
        float4 s0 = v0[c];
        float4 s1 = v1[c];
        a0 += w4.x*s0.x + w4.y*s0.y + w4.z*s0.z + w4.w*s0.w;
        a1 += w4.x*s1.x + w4.y*s1.y + w4.z*s1.z + w4.w*s1.w;
    }
    #pragma unroll
    for (int off = 32; off; off >>= 1) {
        a0 += __shfl_down(a0, off);
        a1 += __shfl_down(a1, off);
    }
    if (lane == 0) {
        float bb = bv[m] * (float)L_;
        S[m]        = a0 + bb;
        S[HDV_ + m] = a1 + bb;
    }
}

// ---- K3: G[b,p,j] = sum_{h%2==p} sum_d S[b,h*DV+d]*fc_w[j,h*DV+d] ----------
// One 256-thread block per j.
__global__ void __launch_bounds__(256) k_fc(const float* __restrict__ S,
                                            const float* __restrict__ fcw,
                                            float* __restrict__ G) {
    __shared__ float red[16];
    int j = blockIdx.x, t = threadIdx.x;
    const float4* row = (const float4*)(fcw + (size_t)j * HDV_);
    const float4* S0  = (const float4*)S;
    const float4* S1  = (const float4*)(S + HDV_);
    float g00 = 0.f, g01 = 0.f, g10 = 0.f, g11 = 0.f;
    #pragma unroll
    for (int it = 0; it < 12; ++it) {           // HDV_/4 = 3072 float4s / 256 thr
        int t4 = it * 256 + t;
        int p  = (t4 / 384) & 1;                // 384 = DV_/4, float4 never straddles
        float4 w4 = row[t4];
        float4 s0 = S0[t4];
        float4 s1 = S1[t4];
        float d0 = w4.x*s0.x + w4.y*s0.y + w4.z*s0.z + w4.w*s0.w;
        float d1 = w4.x*s1.x + w4.y*s1.y + w4.z*s1.z + w4.w*s1.w;
        if (p) { g01 += d0; g11 += d1; } else { g00 += d0; g10 += d1; }
    }
    #pragma unroll
    for (int off = 32; off; off >>= 1) {
        g00 += __shfl_down(g00, off);
        g01 += __shfl_down(g01, off);
        g10 += __shfl_down(g10, off);
        g11 += __shfl_down(g11, off);
    }
    int lane = t & 63, w = t >> 6;
    if (lane == 0) {
        red[w * 4 + 0] = g00; red[w * 4 + 1] = g01;
        red[w * 4 + 2] = g10; red[w * 4 + 3] = g11;
    }
    __syncthreads();
    if (t < 4) {
        float x = red[t] + red[4 + t] + red[8 + t] + red[12 + t];
        G[(size_t)t * D_ + j] = x;              // t: 0=b0p0 1=b0p1 2=b1p0 3=b1p1
    }
}

// ---- K4: out = LayerNorm(q + (m0*G[b,0] + m1*G[b,1]) / L) ------------------
__global__ void __launch_bounds__(256) k_ln(const float* __restrict__ qin,
                                            const int* __restrict__ mask,
                                            const float* __restrict__ G,
                                            const float* __restrict__ lns,
                                            const float* __restrict__ lnb,
                                            float* __restrict__ out) {
    __shared__ float red[8];
    int row = blockIdx.x;            // b*L + q
    int b   = row >> 10;
    int qi  = row & 1023;
    float m0 = (mask[qi]      != 0) ? INV_L : 0.f;
    float m1 = (mask[L_ + qi] != 0) ? INV_L : 0.f;
    const float4* q4 = (const float4*)(qin + (size_t)row * D_);
    const float4* g0 = (const float4*)(G + (size_t)(2 * b) * D_);
    const float4* g1 = (const float4*)(G + (size_t)(2 * b + 1) * D_);
    int t = threadIdx.x;
    float4 a = q4[t], u = g0[t], w = g1[t];
    float4 x;
    x.x = a.x + m0 * u.x + m1 * w.x;
    x.y = a.y + m0 * u.y + m1 * w.y;
    x.z = a.z + m0 * u.z + m1 * w.z;
    x.w = a.w + m0 * u.w + m1 * w.w;
    float s  = x.x + x.y + x.z + x.w;
    float ss = x.x*x.x + x.y*x.y + x.z*x.z + x.w*x.w;
    #pragma unroll
    for (int off = 32; off; off >>= 1) {
        s  += __shfl_down(s, off);
        ss += __shfl_down(ss, off);
    }
    int lane = t & 63, wv = t >> 6;
    if (lane == 0) { red[wv] = s; red[4 + wv] = ss; }
    __syncthreads();
    if (t == 0) {
        float sAll  = red[0] + red[1] + red[2] + red[3];
        float ssAll = red[4] + red[5] + red[6] + red[7];
        float mu  = sAll * INV_L;
        float var = ssAll * INV_L - mu * mu;
        red[0] = mu;
        red[1] = rsqrtf(var + 1e-5f);
    }
    __syncthreads();
    float mu = red[0], inv = red[1];
    float4 sc = ((const float4*)lns)[t];
    float4 bi = ((const float4*)lnb)[t];
    float4 o;
    o.x = (x.x - mu) * inv * sc.x + bi.x;
    o.y = (x.y - mu) * inv * sc.y + bi.y;
    o.z = (x.z - mu) * inv * sc.z + bi.z;
    o.w = (x.w - mu) * inv * sc.w + bi.w;
    ((float4*)(out + (size_t)row * D_))[t] = o;
}

extern "C" void kernel_launch(void* const* d_in, const int* in_sizes, int n_in,
                              void* d_out, int out_size, void* d_ws, size_t ws_size,
                              hipStream_t stream) {
    const float* q    = (const float*)d_in[0];
    const float* v    = (const float*)d_in[2];
    const int*   mask = (const int*)d_in[3];
    const float* wv   = (const float*)d_in[8];   // w_vs_w
    const float* bv   = (const float*)d_in[9];   // w_vs_b
    const float* fcw  = (const float*)d_in[10];  // fc_w
    const float* lns  = (const float*)d_in[11];
    const float* lnb  = (const float*)d_in[12];

    float* out   = (float*)d_out;
    float* atten = out + (size_t)B_ * L_ * D_;

    float* ws   = (float*)d_ws;
    float* vsum = ws;
    float* S    = ws + 2048;
    float* G    = ws + 26624;

    k1      <<<32 + 16384, 256, 0, stream>>>(v, vsum, mask, atten);
    k_vproj <<<(HDV_ * 64) / 256, 256, 0, stream>>>(vsum, wv, bv, S);
    k_fc    <<<D_, 256, 0, stream>>>(S, fcw, G);
    k_ln    <<<B_ * L_, 256, 0, stream>>>(q, mask, G, lns, lnb, out);
}